// Round 1
// baseline (85.464 us; speedup 1.0000x reference)
//
#include <hip/hip_runtime.h>

// ---------------------------------------------------------------------------
// HybridNN: per-sample MLP(2->4->2, tanh) -> 4-layer 2-qubit circuit -> sigmoid
// One thread handles 2 consecutive samples (float4 in / float2 out).
// Rot matrices (constant across batch) precomputed into LDS by threads 0..7.
// ---------------------------------------------------------------------------

struct c2 { float re, im; };

__device__ __forceinline__ c2 cmul(c2 a, c2 b) {
    c2 r;
    r.re = fmaf(a.re, b.re, -(a.im * b.im));
    r.im = fmaf(a.re, b.im, a.im * b.re);
    return r;
}

__device__ __forceinline__ c2 cfma(c2 a, c2 b, c2 acc) {
    acc.re = fmaf(a.re, b.re, fmaf(-a.im, b.im, acc.re));
    acc.im = fmaf(a.re, b.im, fmaf(a.im, b.re, acc.im));
    return acc;
}

// RX-structure gate on a pair of amplitudes: (u,v) <- (c*u - i*s*v, c*v - i*s*u)
__device__ __forceinline__ void rx_pair(c2& u, c2& v, float c, float s) {
    c2 nu, nv;
    nu.re = fmaf(c, u.re,  s * v.im);
    nu.im = fmaf(c, u.im, -(s * v.re));
    nv.re = fmaf(c, v.re,  s * u.im);
    nv.im = fmaf(c, v.im, -(s * u.re));
    u = nu; v = nv;
}

// General 2x2 complex gate: (u,v) <- (g00*u + g01*v, g10*u + g11*v)
__device__ __forceinline__ void rot_pair(c2& u, c2& v, c2 g00, c2 g01, c2 g10, c2 g11) {
    c2 nu = cmul(g00, u); nu = cfma(g01, v, nu);
    c2 nv = cmul(g10, u); nv = cfma(g11, v, nv);
    u = nu; v = nv;
}

__device__ __forceinline__ float ftanh(float v) {
    float e = __expf(2.0f * v);
    return __fdividef(e - 1.0f, e + 1.0f);
}

__global__ __launch_bounds__(256) void hybrid_kernel(
    const float* __restrict__ x,        // (B,2)
    const float* __restrict__ pre_w1,   // (4,2)
    const float* __restrict__ pre_b1,   // (4,)
    const float* __restrict__ pre_w2,   // (2,4)
    const float* __restrict__ pre_b2,   // (2,)
    const float* __restrict__ qw,       // (4,2,3): phi, theta, omega
    const float* __restrict__ post_w,   // (1,2)
    const float* __restrict__ post_b,   // (1,)
    float* __restrict__ out,            // (B,)
    int nbatch)
{
    // Per-layer Rot matrices: Rs[layer][wire][8] = {g00.re,g00.im,g01.re,g01.im,
    //                                              g10.re,g10.im,g11.re,g11.im}
    __shared__ float Rs[4][2][8];
    int tid = threadIdx.x;
    if (tid < 8) {
        int l = tid >> 1, w = tid & 1;
        const float* p = qw + (l * 2 + w) * 3;
        float phi = p[0], th = p[1], om = p[2];
        float c  = cosf(0.5f * th), s = sinf(0.5f * th);
        float a  = 0.5f * (phi + om), b = 0.5f * (phi - om);
        float ca = cosf(a), sa = sinf(a);
        float cb = cosf(b), sb = sinf(b);
        float* r = Rs[l][w];
        // Rot(phi,theta,omega) = [[ep*c, -conj(em)*s], [em*s, conj(ep)*c]]
        // ep = (ca,-sa), em = (cb,-sb)
        r[0] =  c * ca;  r[1] = -c * sa;   // g00
        r[2] = -s * cb;  r[3] = -s * sb;   // g01
        r[4] =  s * cb;  r[5] = -s * sb;   // g10
        r[6] =  c * ca;  r[7] =  c * sa;   // g11
    }
    __syncthreads();

    // Uniform classical weights -> scalar registers
    float w1[8], b1[4], w2[8], b2[2];
#pragma unroll
    for (int i = 0; i < 8; i++) w1[i] = pre_w1[i];
#pragma unroll
    for (int i = 0; i < 4; i++) b1[i] = pre_b1[i];
#pragma unroll
    for (int i = 0; i < 8; i++) w2[i] = pre_w2[i];
#pragma unroll
    for (int i = 0; i < 2; i++) b2[i] = pre_b2[i];
    float pw0 = post_w[0], pw1 = post_w[1], pb = post_b[0];

    int base = (blockIdx.x * blockDim.x + threadIdx.x) * 2;  // first of 2 samples
    if (base >= nbatch) return;

    float4 xin = *reinterpret_cast<const float4*>(x + 2 * (long long)base);
    float xs0[2] = { xin.x, xin.z };
    float xs1[2] = { xin.y, xin.w };
    float res[2];

#pragma unroll
    for (int t = 0; t < 2; t++) {
        float x0 = xs0[t], x1 = xs1[t];

        // --- classical pre-net ---
        float h0 = ftanh(fmaf(w1[0], x0, fmaf(w1[1], x1, b1[0])));
        float h1 = ftanh(fmaf(w1[2], x0, fmaf(w1[3], x1, b1[1])));
        float h2 = ftanh(fmaf(w1[4], x0, fmaf(w1[5], x1, b1[2])));
        float h3 = ftanh(fmaf(w1[6], x0, fmaf(w1[7], x1, b1[3])));
        float g0 = ftanh(fmaf(w2[0], h0, fmaf(w2[1], h1, fmaf(w2[2], h2, fmaf(w2[3], h3, b2[0])))));
        float g1 = ftanh(fmaf(w2[4], h0, fmaf(w2[5], h1, fmaf(w2[6], h2, fmaf(w2[7], h3, b2[1])))));

        // --- per-sample RX gates (same in every layer) ---
        float cs0 = __cosf(0.5f * g0), sn0 = __sinf(0.5f * g0);
        float cs1 = __cosf(0.5f * g1), sn1 = __sinf(0.5f * g1);

        // --- 2-qubit state in registers, |00> init ---
        c2 s00 = {1.0f, 0.0f}, s01 = {0.0f, 0.0f};
        c2 s10 = {0.0f, 0.0f}, s11 = {0.0f, 0.0f};

#pragma unroll
        for (int l = 0; l < 4; l++) {
            // RX(g0) on wire 0
            rx_pair(s00, s10, cs0, sn0);
            rx_pair(s01, s11, cs0, sn0);
            // RX(g1) on wire 1
            rx_pair(s00, s01, cs1, sn1);
            rx_pair(s10, s11, cs1, sn1);
            // Rot on wire 0
            {
                const float* r = Rs[l][0];
                c2 g00 = {r[0], r[1]}, g01 = {r[2], r[3]};
                c2 g10 = {r[4], r[5]}, g11 = {r[6], r[7]};
                rot_pair(s00, s10, g00, g01, g10, g11);
                rot_pair(s01, s11, g00, g01, g10, g11);
            }
            // Rot on wire 1
            {
                const float* r = Rs[l][1];
                c2 g00 = {r[0], r[1]}, g01 = {r[2], r[3]};
                c2 g10 = {r[4], r[5]}, g11 = {r[6], r[7]};
                rot_pair(s00, s01, g00, g01, g10, g11);
                rot_pair(s10, s11, g00, g01, g10, g11);
            }
            // CNOT(0,1): swap s10 <-> s11
            { c2 tmp = s10; s10 = s11; s11 = tmp; }
            // CNOT(1,0): swap s01 <-> s11
            { c2 tmp = s01; s01 = s11; s11 = tmp; }
        }

        // --- measurement ---
        float p00 = fmaf(s00.re, s00.re, s00.im * s00.im);
        float p01 = fmaf(s01.re, s01.re, s01.im * s01.im);
        float p10 = fmaf(s10.re, s10.re, s10.im * s10.im);
        float p11 = fmaf(s11.re, s11.re, s11.im * s11.im);
        float z0 = (p00 + p01) - (p10 + p11);
        float z1 = (p00 + p10) - (p01 + p11);

        // --- classical post-net ---
        float q0 = 0.5f * (z0 + 1.0f);
        float q1 = 0.5f * (z1 + 1.0f);
        float y  = fmaf(pw0, q0, fmaf(pw1, q1, pb));
        res[t] = __fdividef(1.0f, 1.0f + __expf(-y));
    }

    *reinterpret_cast<float2*>(out + base) = make_float2(res[0], res[1]);
}

extern "C" void kernel_launch(void* const* d_in, const int* in_sizes, int n_in,
                              void* d_out, int out_size, void* d_ws, size_t ws_size,
                              hipStream_t stream) {
    const float* x      = (const float*)d_in[0];
    const float* pre_w1 = (const float*)d_in[1];
    const float* pre_b1 = (const float*)d_in[2];
    const float* pre_w2 = (const float*)d_in[3];
    const float* pre_b2 = (const float*)d_in[4];
    const float* qw     = (const float*)d_in[5];
    const float* post_w = (const float*)d_in[6];
    const float* post_b = (const float*)d_in[7];
    float* out = (float*)d_out;

    int nbatch  = in_sizes[0] / 2;          // (B,2) input
    int threads = 256;
    int spb     = threads * 2;              // samples per block
    int blocks  = (nbatch + spb - 1) / spb;
    hipLaunchKernelGGL(hybrid_kernel, dim3(blocks), dim3(threads), 0, stream,
                       x, pre_w1, pre_b1, pre_w2, pre_b2, qw, post_w, post_b,
                       out, nbatch);
}

// Round 2
// 78.867 us; speedup vs baseline: 1.0837x; 1.0837x over previous
//
#include <hip/hip_runtime.h>

// ---------------------------------------------------------------------------
// HybridNN via 2-D lookup table.
// Insight: the full network output y is a function of ONLY the two layer-2
// pre-activations (u0, u1) (g = tanh(u) feeds the quantum circuit + post-net).
// Kernel 1 tabulates y = F(u0,u1) on a 256x256 grid over the provable range
// [-B, B], B = sum|w2| + |b2|.  Kernel 2 does MLP layer 1 + bilinear lookup.
// ---------------------------------------------------------------------------

#define TN 256   // table points per dimension (256 KB table in d_ws)

struct c2 { float re, im; };

__device__ __forceinline__ c2 cmul(c2 a, c2 b) {
    c2 r;
    r.re = fmaf(a.re, b.re, -(a.im * b.im));
    r.im = fmaf(a.re, b.im, a.im * b.re);
    return r;
}

__device__ __forceinline__ c2 cfma(c2 a, c2 b, c2 acc) {
    acc.re = fmaf(a.re, b.re, fmaf(-a.im, b.im, acc.re));
    acc.im = fmaf(a.re, b.im, fmaf(a.im, b.re, acc.im));
    return acc;
}

__device__ __forceinline__ void rx_pair(c2& u, c2& v, float c, float s) {
    c2 nu, nv;
    nu.re = fmaf(c, u.re,  s * v.im);
    nu.im = fmaf(c, u.im, -(s * v.re));
    nv.re = fmaf(c, v.re,  s * u.im);
    nv.im = fmaf(c, v.im, -(s * u.re));
    u = nu; v = nv;
}

__device__ __forceinline__ void rot_pair(c2& u, c2& v, c2 g00, c2 g01, c2 g10, c2 g11) {
    c2 nu = cmul(g00, u); nu = cfma(g01, v, nu);
    c2 nv = cmul(g10, u); nv = cfma(g11, v, nv);
    u = nu; v = nv;
}

__device__ __forceinline__ float ftanh(float v) {
    float e = __expf(2.0f * v);
    return __fdividef(e - 1.0f, e + 1.0f);
}

// u-range bounds; MUST be computed identically in both kernels.
__device__ __forceinline__ void u_bounds(const float* w2, const float* b2,
                                         float& B0, float& B1) {
    B0 = fabsf(w2[0]) + fabsf(w2[1]) + fabsf(w2[2]) + fabsf(w2[3]) + fabsf(b2[0]);
    B1 = fabsf(w2[4]) + fabsf(w2[5]) + fabsf(w2[6]) + fabsf(w2[7]) + fabsf(b2[1]);
}

// Full circuit + post-net given the two embedding angles g0,g1.
__device__ __forceinline__ float circuit_y(float g0, float g1,
                                           const float (*Rs)[2][8],
                                           float pw0, float pw1, float pb) {
    float cs0 = __cosf(0.5f * g0), sn0 = __sinf(0.5f * g0);
    float cs1 = __cosf(0.5f * g1), sn1 = __sinf(0.5f * g1);

    c2 s00 = {1.0f, 0.0f}, s01 = {0.0f, 0.0f};
    c2 s10 = {0.0f, 0.0f}, s11 = {0.0f, 0.0f};

#pragma unroll
    for (int l = 0; l < 4; l++) {
        rx_pair(s00, s10, cs0, sn0);
        rx_pair(s01, s11, cs0, sn0);
        rx_pair(s00, s01, cs1, sn1);
        rx_pair(s10, s11, cs1, sn1);
        {
            const float* r = Rs[l][0];
            c2 g00 = {r[0], r[1]}, g01 = {r[2], r[3]};
            c2 g10 = {r[4], r[5]}, g11 = {r[6], r[7]};
            rot_pair(s00, s10, g00, g01, g10, g11);
            rot_pair(s01, s11, g00, g01, g10, g11);
        }
        {
            const float* r = Rs[l][1];
            c2 g00 = {r[0], r[1]}, g01 = {r[2], r[3]};
            c2 g10 = {r[4], r[5]}, g11 = {r[6], r[7]};
            rot_pair(s00, s01, g00, g01, g10, g11);
            rot_pair(s10, s11, g00, g01, g10, g11);
        }
        { c2 tmp = s10; s10 = s11; s11 = tmp; }  // CNOT(0,1)
        { c2 tmp = s01; s01 = s11; s11 = tmp; }  // CNOT(1,0)
    }

    float p00 = fmaf(s00.re, s00.re, s00.im * s00.im);
    float p01 = fmaf(s01.re, s01.re, s01.im * s01.im);
    float p10 = fmaf(s10.re, s10.re, s10.im * s10.im);
    float p11 = fmaf(s11.re, s11.re, s11.im * s11.im);
    float z0 = (p00 + p01) - (p10 + p11);
    float z1 = (p00 + p10) - (p01 + p11);

    float q0 = 0.5f * (z0 + 1.0f);
    float q1 = 0.5f * (z1 + 1.0f);
    float y  = fmaf(pw0, q0, fmaf(pw1, q1, pb));
    return __fdividef(1.0f, 1.0f + __expf(-y));
}

// ---------------------------------------------------------------------------
// Kernel 1: tabulate y = F(u0,u1), 256x256 grid.  65536 threads.
// ---------------------------------------------------------------------------
__global__ __launch_bounds__(256) void build_table(
    const float* __restrict__ qw,      // (4,2,3)
    const float* __restrict__ pre_w2,  // (2,4)
    const float* __restrict__ pre_b2,  // (2,)
    const float* __restrict__ post_w,  // (1,2)
    const float* __restrict__ post_b,  // (1,)
    float* __restrict__ table)         // (TN*TN,)
{
    __shared__ float Rs[4][2][8];
    int tid = threadIdx.x;
    if (tid < 8) {
        int l = tid >> 1, w = tid & 1;
        const float* p = qw + (l * 2 + w) * 3;
        float phi = p[0], th = p[1], om = p[2];
        float c  = cosf(0.5f * th), s = sinf(0.5f * th);
        float a  = 0.5f * (phi + om), b = 0.5f * (phi - om);
        float ca = cosf(a), sa = sinf(a);
        float cb = cosf(b), sb = sinf(b);
        float* r = Rs[l][w];
        r[0] =  c * ca;  r[1] = -c * sa;   // g00
        r[2] = -s * cb;  r[3] = -s * sb;   // g01
        r[4] =  s * cb;  r[5] = -s * sb;   // g10
        r[6] =  c * ca;  r[7] =  c * sa;   // g11
    }
    __syncthreads();

    int k = blockIdx.x * 256 + tid;
    int i = k & (TN - 1);
    int j = k >> 8;

    float B0, B1;
    u_bounds(pre_w2, pre_b2, B0, B1);

    float u0 = fmaf((2.0f * B0) / (float)(TN - 1), (float)i, -B0);
    float u1 = fmaf((2.0f * B1) / (float)(TN - 1), (float)j, -B1);
    float g0 = ftanh(u0);
    float g1 = ftanh(u1);

    table[k] = circuit_y(g0, g1, Rs, post_w[0], post_w[1], post_b[0]);
}

// ---------------------------------------------------------------------------
// Kernel 2: per-sample MLP layer 1 + bilinear table lookup. 2 samples/thread.
// ---------------------------------------------------------------------------
__global__ __launch_bounds__(256) void eval_kernel(
    const float* __restrict__ x,       // (B,2)
    const float* __restrict__ pre_w1,  // (4,2)
    const float* __restrict__ pre_b1,  // (4,)
    const float* __restrict__ pre_w2,  // (2,4)
    const float* __restrict__ pre_b2,  // (2,)
    const float* __restrict__ table,   // (TN*TN,)
    float* __restrict__ out,           // (B,)
    int nbatch)
{
    float w1[8], b1[4], w2[8], b2[2];
#pragma unroll
    for (int i = 0; i < 8; i++) w1[i] = pre_w1[i];
#pragma unroll
    for (int i = 0; i < 4; i++) b1[i] = pre_b1[i];
#pragma unroll
    for (int i = 0; i < 8; i++) w2[i] = pre_w2[i];
#pragma unroll
    for (int i = 0; i < 2; i++) b2[i] = pre_b2[i];

    float B0, B1;
    u_bounds(w2, b2, B0, B1);
    float sc0 = (float)(TN - 1) / (2.0f * B0);
    float sc1 = (float)(TN - 1) / (2.0f * B1);

    int base = (blockIdx.x * blockDim.x + threadIdx.x) * 2;
    if (base >= nbatch) return;

    float4 xin = *reinterpret_cast<const float4*>(x + 2 * (long long)base);
    float xs0[2] = { xin.x, xin.z };
    float xs1[2] = { xin.y, xin.w };
    float res[2];

#pragma unroll
    for (int t = 0; t < 2; t++) {
        float x0 = xs0[t], x1 = xs1[t];

        float h0 = ftanh(fmaf(w1[0], x0, fmaf(w1[1], x1, b1[0])));
        float h1 = ftanh(fmaf(w1[2], x0, fmaf(w1[3], x1, b1[1])));
        float h2 = ftanh(fmaf(w1[4], x0, fmaf(w1[5], x1, b1[2])));
        float h3 = ftanh(fmaf(w1[6], x0, fmaf(w1[7], x1, b1[3])));

        float u0 = fmaf(w2[0], h0, fmaf(w2[1], h1, fmaf(w2[2], h2, fmaf(w2[3], h3, b2[0]))));
        float u1 = fmaf(w2[4], h0, fmaf(w2[5], h1, fmaf(w2[6], h2, fmaf(w2[7], h3, b2[1]))));

        // grid coordinates, clamped
        float t0 = (u0 + B0) * sc0;
        float t1 = (u1 + B1) * sc1;
        t0 = fminf(fmaxf(t0, 0.0f), (float)(TN - 1));
        t1 = fminf(fmaxf(t1, 0.0f), (float)(TN - 1));
        float i0f = fminf(floorf(t0), (float)(TN - 2));
        float j0f = fminf(floorf(t1), (float)(TN - 2));
        float f0 = t0 - i0f;
        float f1 = t1 - j0f;
        int i0 = (int)i0f;
        int j0 = (int)j0f;

        const float* p = table + j0 * TN + i0;
        float a = p[0], b = p[1], c = p[TN], d = p[TN + 1];
        float top = fmaf(f0, b - a, a);
        float bot = fmaf(f0, d - c, c);
        res[t] = fmaf(f1, bot - top, top);
    }

    *reinterpret_cast<float2*>(out + base) = make_float2(res[0], res[1]);
}

extern "C" void kernel_launch(void* const* d_in, const int* in_sizes, int n_in,
                              void* d_out, int out_size, void* d_ws, size_t ws_size,
                              hipStream_t stream) {
    const float* x      = (const float*)d_in[0];
    const float* pre_w1 = (const float*)d_in[1];
    const float* pre_b1 = (const float*)d_in[2];
    const float* pre_w2 = (const float*)d_in[3];
    const float* pre_b2 = (const float*)d_in[4];
    const float* qw     = (const float*)d_in[5];
    const float* post_w = (const float*)d_in[6];
    const float* post_b = (const float*)d_in[7];
    float* out   = (float*)d_out;
    float* table = (float*)d_ws;   // TN*TN floats = 256 KB

    // 1) build the (u0,u1) -> y table (d_ws is re-poisoned every call, so
    //    this must run every call — it does).
    hipLaunchKernelGGL(build_table, dim3((TN * TN) / 256), dim3(256), 0, stream,
                       qw, pre_w2, pre_b2, post_w, post_b, table);

    // 2) per-sample MLP layer 1 + bilinear lookup
    int nbatch  = in_sizes[0] / 2;
    int threads = 256;
    int spb     = threads * 2;
    int blocks  = (nbatch + spb - 1) / spb;
    hipLaunchKernelGGL(eval_kernel, dim3(blocks), dim3(threads), 0, stream,
                       x, pre_w1, pre_b1, pre_w2, pre_b2, table, out, nbatch);
}